// Round 12
// baseline (3261.399 us; speedup 1.0000x reference)
//
#include <hip/hip_runtime.h>
#include <hip/hip_bf16.h>
#include <math.h>

#define N_NODES 10000
#define N_EDGES 160000
#define IN_DIM  512
#define HID     1024
#define M_PAD   10240   // 40 * 256 (also 80 * 128)

typedef _Float16 half8 __attribute__((ext_vector_type(8)));
typedef float    floatx4 __attribute__((ext_vector_type(4)));

__device__ inline void gld16(const void* g, void* l) {
    __builtin_amdgcn_global_load_lds(
        (const __attribute__((address_space(1))) unsigned int*)g,
        (__attribute__((address_space(3))) unsigned int*)l, 16, 0, 0);
}

__device__ inline float sig_(float x)  { return 1.0f / (1.0f + __expf(-x)); }
__device__ inline float tanh_(float x) { return 2.0f / (1.0f + __expf(-2.0f * x)) - 1.0f; }

// Supertile swizzle: 4 consecutive linear block ids share one x (A-tile).
// gemm_f16 only (r6 win); gates without (r6 loss).
__device__ inline void swizzle_xy(int& bx, int& by) {
    int lin = blockIdx.y * gridDim.x + blockIdx.x;
    int per = gridDim.x << 2;
    int sup = lin / per;
    int rem = lin - sup * per;
    by = (sup << 2) + (rem & 3);
    bx = rem >> 2;
}

// ---------------------------------------------------------------------------
// CSR build
// ---------------------------------------------------------------------------
__global__ void k_hist(const int* __restrict__ ei, int* __restrict__ deg, int ne) {
    int e = blockIdx.x * blockDim.x + threadIdx.x;
    if (e < ne) atomicAdd(&deg[ei[2 * e + 1]], 1);
}

// exclusive scan; writes offs[0..n] and a second copy into cur[0..n-1]
__global__ void k_scan(const int* __restrict__ deg, int* __restrict__ offs,
                       int* __restrict__ cur, int n) {
    __shared__ int s[1024];
    __shared__ int base_s;
    int t = threadIdx.x;
    if (t == 0) base_s = 0;
    __syncthreads();
    int nchunk = (n + 1023) / 1024;
    for (int ch = 0; ch < nchunk; ++ch) {
        int i = ch * 1024 + t;
        int v = (i < n) ? deg[i] : 0;
        s[t] = v;
        __syncthreads();
        for (int off = 1; off < 1024; off <<= 1) {
            int add = (t >= off) ? s[t - off] : 0;
            __syncthreads();
            s[t] += add;
            __syncthreads();
        }
        int incl = s[t];
        int base = base_s;
        if (i < n) { int ex = base + incl - v; offs[i] = ex; cur[i] = ex; }
        __syncthreads();
        if (t == 1023) base_s = base + s[1023];
        __syncthreads();
    }
    if (t == 0) offs[n] = base_s;
}

// scatter packed (dir<<16)|src; also zero-inits hmax (cols < HID)
__global__ void k_scatter(const int* __restrict__ ei, const int* __restrict__ ed,
                          int* __restrict__ cur, int* __restrict__ esort,
                          float* __restrict__ hmax, int ne) {
    int e = blockIdx.x * blockDim.x + threadIdx.x;
    if (e < HID) hmax[e] = 0.f;
    if (e < ne) {
        int dst = ei[2 * e + 1];
        int pos = atomicAdd(&cur[dst], 1);
        esort[pos] = (ed[e] << 16) | ei[2 * e];
    }
}

// fp32->fp16 feature convert + bias precompute (fused)
__global__ void k_cvt_prep(const float* __restrict__ X, _Float16* __restrict__ Xh,
                           int n, const float* __restrict__ b_f,
                           const float* __restrict__ b_b,
                           const float* __restrict__ b_ih,
                           const float* __restrict__ b_hh,
                           float* __restrict__ bfb, float* __restrict__ brz) {
    int i = blockIdx.x * blockDim.x + threadIdx.x;
    if (i < n) Xh[i] = (_Float16)X[i];
    if (i < HID) bfb[i] = b_f[i] + b_b[i];
    if (i < 2 * HID) brz[i] = b_ih[i] + b_hh[i];
}

// All 5 weight transposes (fp32 KxN -> fp16 NxK) in one dispatch via tile table
__global__ __launch_bounds__(256) void k_transpose_all(
    const float* __restrict__ W_in, const float* __restrict__ W_f,
    const float* __restrict__ W_b, const float* __restrict__ W_ih,
    const float* __restrict__ W_hh,
    _Float16* __restrict__ Wint, _Float16* __restrict__ Wft,
    _Float16* __restrict__ Wbt, _Float16* __restrict__ Wiht,
    _Float16* __restrict__ Whht) {
    int tid = blockIdx.x;
    const float* in; _Float16* outp; int K, N, loc;
    if (tid < 512)       { in = W_in; outp = Wint; K = IN_DIM; N = HID;     loc = tid; }
    else if (tid < 1536) { in = W_f;  outp = Wft;  K = HID;    N = HID;     loc = tid - 512; }
    else if (tid < 2560) { in = W_b;  outp = Wbt;  K = HID;    N = HID;     loc = tid - 1536; }
    else if (tid < 5632) { in = W_ih; outp = Wiht; K = HID;    N = 3 * HID; loc = tid - 2560; }
    else                 { in = W_hh; outp = Whht; K = HID;    N = 3 * HID; loc = tid - 5632; }
    int nt = N >> 5;
    int n0 = (loc % nt) * 32, k0 = (loc / nt) * 32;
    __shared__ float tile[32][33];
    int tx = threadIdx.x & 31, ty = threadIdx.x >> 5;   // 32 x 8
#pragma unroll
    for (int r = 0; r < 4; ++r) {
        int k = k0 + ty + r * 8;
        tile[ty + r * 8][tx] = in[(size_t)k * N + n0 + tx];
    }
    __syncthreads();
#pragma unroll
    for (int r = 0; r < 4; ++r) {
        int n = n0 + ty + r * 8;
        outp[(size_t)n * K + k0 + tx] = (_Float16)tile[tx][ty + r * 8];
    }
}

// ---------------------------------------------------------------------------
// Aggregation: one block (128 thr) per node, 8 fp16 channels each.
// 4x edge unroll; wave-uniform branches with DIRECT register arrays
// (r10 lesson: runtime-selected pointer -> scratch spill, 517 MB writes).
// Structural floor ~90 us/layer: random 2KB row-gather at ~3.6 TB/s (r11).
// ---------------------------------------------------------------------------
__global__ __launch_bounds__(128) void k_agg(
    const _Float16* __restrict__ h, const int* __restrict__ offs,
    const int* __restrict__ esort,
    _Float16* __restrict__ aggF, _Float16* __restrict__ aggB,
    _Float16* __restrict__ aggU) {
    int node = blockIdx.x;
    int c = threadIdx.x * 8;
    float f[8], b[8], u[8];
#pragma unroll
    for (int j = 0; j < 8; ++j) { f[j] = 0.f; b[j] = 0.f; u[j] = 0.f; }
    int beg = offs[node], end = offs[node + 1];
    int e = beg;
    for (; e + 4 <= end; e += 4) {
        int pk0 = esort[e + 0];
        int pk1 = esort[e + 1];
        int pk2 = esort[e + 2];
        int pk3 = esort[e + 3];
        half8 v0 = *(const half8*)(h + ((size_t)(pk0 & 0xFFFF) << 10) + c);
        half8 v1 = *(const half8*)(h + ((size_t)(pk1 & 0xFFFF) << 10) + c);
        half8 v2 = *(const half8*)(h + ((size_t)(pk2 & 0xFFFF) << 10) + c);
        half8 v3 = *(const half8*)(h + ((size_t)(pk3 & 0xFFFF) << 10) + c);
        int d0 = pk0 >> 16, d1 = pk1 >> 16, d2 = pk2 >> 16, d3 = pk3 >> 16;
        if (d0 == 0) {
#pragma unroll
            for (int j = 0; j < 8; ++j) f[j] += (float)v0[j];
        } else if (d0 == 1) {
#pragma unroll
            for (int j = 0; j < 8; ++j) b[j] += (float)v0[j];
        } else {
#pragma unroll
            for (int j = 0; j < 8; ++j) u[j] += (float)v0[j];
        }
        if (d1 == 0) {
#pragma unroll
            for (int j = 0; j < 8; ++j) f[j] += (float)v1[j];
        } else if (d1 == 1) {
#pragma unroll
            for (int j = 0; j < 8; ++j) b[j] += (float)v1[j];
        } else {
#pragma unroll
            for (int j = 0; j < 8; ++j) u[j] += (float)v1[j];
        }
        if (d2 == 0) {
#pragma unroll
            for (int j = 0; j < 8; ++j) f[j] += (float)v2[j];
        } else if (d2 == 1) {
#pragma unroll
            for (int j = 0; j < 8; ++j) b[j] += (float)v2[j];
        } else {
#pragma unroll
            for (int j = 0; j < 8; ++j) u[j] += (float)v2[j];
        }
        if (d3 == 0) {
#pragma unroll
            for (int j = 0; j < 8; ++j) f[j] += (float)v3[j];
        } else if (d3 == 1) {
#pragma unroll
            for (int j = 0; j < 8; ++j) b[j] += (float)v3[j];
        } else {
#pragma unroll
            for (int j = 0; j < 8; ++j) u[j] += (float)v3[j];
        }
    }
    for (; e < end; ++e) {
        int pk = esort[e];
        half8 v = *(const half8*)(h + ((size_t)(pk & 0xFFFF) << 10) + c);
        int d = pk >> 16;
        if (d == 0) {
#pragma unroll
            for (int j = 0; j < 8; ++j) f[j] += (float)v[j];
        } else if (d == 1) {
#pragma unroll
            for (int j = 0; j < 8; ++j) b[j] += (float)v[j];
        } else {
#pragma unroll
            for (int j = 0; j < 8; ++j) u[j] += (float)v[j];
        }
    }
    size_t o = (size_t)node * HID + c;
    half8 vf, vb, vu;
#pragma unroll
    for (int j = 0; j < 8; ++j) {
        vf[j] = (_Float16)f[j]; vb[j] = (_Float16)b[j]; vu[j] = (_Float16)u[j];
    }
    *(half8*)(aggF + o) = vf;
    *(half8*)(aggB + o) = vb;
    *(half8*)(aggU + o) = vu;
}

// ---------------------------------------------------------------------------
// fp16 MFMA GEMM, 128x256 tile, BK=32, 512 thr = 8 waves (2m x 4n), each wave
// a 64x64 microtile of 4x4 mfma_f32_16x16x32_f16. Output width fixed = HID.
// NOTE: VGPR budget sits at the 4-waves/SIMD boundary (60 VGPR + 64 acc);
// any VGPR creep halves occupancy (r7: BK=64 -> 80 VGPR -> 1 blk/CU).
// epi 0: v = acc+bias [+U]; Cbf = v
// epi 2: GRU in place: hv=Cbf; nn=tanh(acc+bias+R*HG); Cbf=relu((1-Z)nn+Z*hv)
// ---------------------------------------------------------------------------
#define BM 128
#define BN 256
#define BK 32
#define NTHR 512

__global__ __launch_bounds__(NTHR) void gemm_f16(
    const _Float16* __restrict__ A1, const _Float16* __restrict__ B1t,
    const _Float16* __restrict__ A2, const _Float16* __restrict__ B2t,
    const _Float16* __restrict__ U, const float* __restrict__ bias,
    const _Float16* __restrict__ R, const _Float16* __restrict__ Zg,
    const _Float16* __restrict__ HG, _Float16* __restrict__ Cbf,
    int M, int K, int epi) {
    __shared__ _Float16 As[BM * BK];   // 8 KB
    __shared__ _Float16 Bs[BN * BK];   // 16 KB
    int t = threadIdx.x;
    int bx, by;
    swizzle_xy(bx, by);
    int m0 = bx * BM, n0 = by * BN;
    int wid = t >> 6, lane = t & 63;
    int wm = wid & 1, wn = wid >> 1;            // 2 x 4 wave grid
    int quad = lane >> 4, mr = lane & 15;

    floatx4 acc[4][4] = {};

    int npair = (A2 != nullptr) ? 2 : 1;
    for (int p = 0; p < npair; ++p) {
        const _Float16* A = p ? A2 : A1;
        const _Float16* B = p ? B2t : B1t;
        for (int k0 = 0; k0 < K; k0 += BK) {
            {   // A tile 128x32: 1 gld16 per thread
                int row = t >> 2;
                int ce = (t & 3) * 8;
                gld16(A + (size_t)(m0 + row) * K + k0 + ce, As + t * 8);
            }
#pragma unroll
            for (int i = 0; i < 2; ++i) {       // B tile 256x32: 2 gld16
                int row = i * 128 + (t >> 2);
                int ce = (t & 3) * 8;
                gld16(B + (size_t)(n0 + row) * K + k0 + ce, Bs + i * 4096 + t * 8);
            }
            __syncthreads();
            half8 af[4], bfr[4];
#pragma unroll
            for (int i = 0; i < 4; ++i)
                af[i] = *(const half8*)(As + (wm * 64 + i * 16 + mr) * 32 + quad * 8);
#pragma unroll
            for (int j = 0; j < 4; ++j)
                bfr[j] = *(const half8*)(Bs + (wn * 64 + j * 16 + mr) * 32 + quad * 8);
#pragma unroll
            for (int i = 0; i < 4; ++i)
#pragma unroll
                for (int j = 0; j < 4; ++j)
                    acc[i][j] = __builtin_amdgcn_mfma_f32_16x16x32_f16(
                        af[i], bfr[j], acc[i][j], 0, 0, 0);
            __syncthreads();
        }
    }

#pragma unroll
    for (int i = 0; i < 4; ++i) {
#pragma unroll
        for (int j = 0; j < 4; ++j) {
            int n = n0 + wn * 64 + j * 16 + mr;
            float bv = bias[n];
#pragma unroll
            for (int r = 0; r < 4; ++r) {
                int m = m0 + wm * 64 + i * 16 + quad * 4 + r;
                if (m >= M) continue;
                size_t idx = (size_t)m * HID + n;
                float v = acc[i][j][r] + bv;
                if (epi == 0) {
                    if (U) v += (float)U[idx];
                    Cbf[idx] = (_Float16)v;
                } else {
                    float rr = (float)R[idx], zz = (float)Zg[idx], hg = (float)HG[idx];
                    float hv = (float)Cbf[idx];
                    float nn = tanh_(v + rr * hg);
                    float o = fmaxf((1.f - zz) * nn + zz * hv, 0.f);
                    Cbf[idx] = (_Float16)o;
                }
            }
        }
    }
}

// ---------------------------------------------------------------------------
// Fused gate GEMM, 256x256 tile, BK=32, 1024 thr = 16 waves (4m x 4n).
// Same per-wave microtile / per-thread staging (1 gld16 A + 1 gld16 B) and
// acc count (64 VGPR) as the proven 128x256 config; block count halves ->
// 33% less staging traffic, 1.5x MFMA:staging ratio.
//   ng0 in [0,2048):   C = sigmoid(msg@Wih[n] + h@Whh[n] + brz[n])  (r, z)
//   ng0 in [2048,3072): C = h@Whh[n] + b_hh[n]                      (hn-gate)
// Writes r->bufA, z->bufB, hn->bufC. No block swizzle (r6 regression).
// ---------------------------------------------------------------------------
#define GM 256
#define GN 256

__global__ __launch_bounds__(1024) void gemm_gates(
    const _Float16* __restrict__ msg, const _Float16* __restrict__ hbf,
    const _Float16* __restrict__ Wiht, const _Float16* __restrict__ Whht,
    const float* __restrict__ brz, const float* __restrict__ b_hh,
    _Float16* __restrict__ bufA, _Float16* __restrict__ bufB,
    _Float16* __restrict__ bufC, int M) {
    __shared__ _Float16 As[GM * BK];   // 16 KB
    __shared__ _Float16 Bs[GN * BK];   // 16 KB
    int t = threadIdx.x;
    int m0 = blockIdx.x * GM;
    int ng0 = blockIdx.y * GN;          // global n in [0, 3072), 256-aligned
    int seg = ng0 >> 10;                // 0=r, 1=z, 2=hn
    int wid = t >> 6, lane = t & 63;
    int wm = wid & 3, wn = wid >> 2;    // 4 x 4 wave grid
    int quad = lane >> 4, mr = lane & 15;

    const _Float16* A1 = (seg < 2) ? msg : hbf;
    const _Float16* B1 = ((seg < 2) ? Wiht : Whht) + (size_t)ng0 * HID;
    const _Float16* A2 = hbf;
    const _Float16* B2 = Whht + (size_t)ng0 * HID;
    int npair = (seg < 2) ? 2 : 1;

    floatx4 acc[4][4] = {};
    for (int p = 0; p < npair; ++p) {
        const _Float16* A = p ? A2 : A1;
        const _Float16* B = p ? B2 : B1;
        for (int k0 = 0; k0 < HID; k0 += BK) {
            int row = t >> 2;
            int ce = (t & 3) * 8;
            gld16(A + (size_t)(m0 + row) * HID + k0 + ce, As + t * 8);
            gld16(B + (size_t)row * HID + k0 + ce, Bs + t * 8);
            __syncthreads();
            half8 af[4], bfr[4];
#pragma unroll
            for (int i = 0; i < 4; ++i)
                af[i] = *(const half8*)(As + (wm * 64 + i * 16 + mr) * 32 + quad * 8);
#pragma unroll
            for (int j = 0; j < 4; ++j)
                bfr[j] = *(const half8*)(Bs + (wn * 64 + j * 16 + mr) * 32 + quad * 8);
#pragma unroll
            for (int i = 0; i < 4; ++i)
#pragma unroll
                for (int j = 0; j < 4; ++j)
                    acc[i][j] = __builtin_amdgcn_mfma_f32_16x16x32_f16(
                        af[i], bfr[j], acc[i][j], 0, 0, 0);
            __syncthreads();
        }
    }

    _Float16* Cb = (seg == 0) ? bufA : (seg == 1) ? bufB : bufC;
#pragma unroll
    for (int i = 0; i < 4; ++i) {
#pragma unroll
        for (int j = 0; j < 4; ++j) {
            int n = ng0 + wn * 64 + j * 16 + mr;       // global [0,3072)
            int nloc = n & 1023;
            float bv = (seg < 2) ? brz[n] : b_hh[n];
#pragma unroll
            for (int r = 0; r < 4; ++r) {
                int m = m0 + wm * 64 + i * 16 + quad * 4 + r;
                if (m >= M) continue;
                size_t idx = (size_t)m * HID + nloc;
                float v = acc[i][j][r] + bv;
                Cb[idx] = (_Float16)((seg < 2) ? sig_(v) : v);
            }
        }
    }
}

// ---------------------------------------------------------------------------
// Readout
// ---------------------------------------------------------------------------
// colmax: block = 128 thr x 8 channels (coalesced 2 KB/row); grid (1, 50)
__global__ __launch_bounds__(128) void k_colmax(const _Float16* __restrict__ h,
                                                float* __restrict__ hmax) {
    int c = threadIdx.x * 8;
    int r0 = blockIdx.y * 200;
    int r1 = r0 + 200; if (r1 > N_NODES) r1 = N_NODES;
    float m[8];
#pragma unroll
    for (int j = 0; j < 8; ++j) m[j] = 0.f;             // h >= 0 post-relu
    for (int r = r0; r < r1; ++r) {
        half8 v = *(const half8*)(h + ((size_t)r << 10) + c);
#pragma unroll
        for (int j = 0; j < 8; ++j) m[j] = fmaxf(m[j], (float)v[j]);
    }
#pragma unroll
    for (int j = 0; j < 8; ++j)
        atomicMax((int*)&hmax[c + j], __float_as_int(m[j]));
}

// fused: t1 = relu(hmax@W_r1 + b_r1); out = t1@W_r2 + b_r2  (one block, 1024 thr)
__global__ __launch_bounds__(1024) void k_readout(
    const float* __restrict__ hmax, const float* __restrict__ W1,
    const float* __restrict__ b1, const float* __restrict__ W2,
    const float* __restrict__ b2, float* __restrict__ out) {
    __shared__ float sh[1024];
    int j = threadIdx.x;
    float acc = b1[j];
    for (int k = 0; k < HID; ++k) acc += hmax[k] * W1[(size_t)k * HID + j];
    sh[j] = fmaxf(acc, 0.f) * W2[j];
    __syncthreads();
    for (int st = 512; st > 0; st >>= 1) {
        if (j < st) sh[j] += sh[j + st];
        __syncthreads();
    }
    if (j == 0) out[0] = sh[0] + b2[0];
}

// ---------------------------------------------------------------------------
extern "C" void kernel_launch(void* const* d_in, const int* in_sizes, int n_in,
                              void* d_out, int out_size, void* d_ws, size_t ws_size,
                              hipStream_t stream) {
    const float* node_features = (const float*)d_in[0];
    const int*   edge_index    = (const int*)d_in[1];
    const int*   edge_dirs     = (const int*)d_in[2];
    const float* W_in = (const float*)d_in[3];
    const float* b_in = (const float*)d_in[4];
    const float* W_f  = (const float*)d_in[5];
    const float* b_f  = (const float*)d_in[6];
    const float* W_b  = (const float*)d_in[7];
    const float* b_b  = (const float*)d_in[8];
    const float* W_ih = (const float*)d_in[9];
    const float* b_ih = (const float*)d_in[10];
    const float* W_hh = (const float*)d_in[11];
    const float* b_hh = (const float*)d_in[12];
    const float* W_r1 = (const float*)d_in[13];
    const float* b_r1 = (const float*)d_in[14];
    const float* W_r2 = (const float*)d_in[15];
    const float* b_r2 = (const float*)d_in[16];
    float* out = (float*)d_out;

    // ---- workspace layout ----
    float* ws = (float*)d_ws;
    size_t off = 0;
    auto allocf = [&](size_t n) { float* p = ws + off; off += n; return p; };
    const size_t PH = (size_t)M_PAD * HID;
    float* bfb   = allocf(HID);
    float* brz   = allocf(2 * HID);
    float* hmax  = allocf(HID);
    _Float16* hp = (_Float16*)(ws + off);
    size_t hoff = 0;
    auto alloch = [&](size_t n) { _Float16* p = hp + hoff; hoff += n; return p; };
    _Float16* h_bf  = alloch(PH);       // fp16 GRU state (in-place update)
    _Float16* msg   = alloch(PH);
    _Float16* bufA  = alloch(PH);       // aggF -> r
    _Float16* bufB  = alloch(PH);       // aggB -> z
    _Float16* bufC  = alloch(PH);       // aggU -> hn-gate
    _Float16* X_bf  = alloch((size_t)M_PAD * IN_DIM);
    _Float16* Wint  = alloch((size_t)HID * IN_DIM);
    _Float16* Wft   = alloch((size_t)HID * HID);
    _Float16* Wbt   = alloch((size_t)HID * HID);
    _Float16* Wiht  = alloch((size_t)3 * HID * HID);   // 3072 x 1024 (N x K)
    _Float16* Whht  = alloch((size_t)3 * HID * HID);
    int* ibase = (int*)(hp + hoff);
    int* deg   = ibase;
    int* offs  = ibase + N_NODES;
    int* cur   = offs + N_NODES + 1;
    int* esort = cur + N_NODES;

    // ---- CSR build + prep ----
    hipMemsetAsync(deg, 0, N_NODES * sizeof(int), stream);
    k_hist<<<(N_EDGES + 255) / 256, 256, 0, stream>>>(edge_index, deg, N_EDGES);
    k_scan<<<1, 1024, 0, stream>>>(deg, offs, cur, N_NODES);
    k_scatter<<<(N_EDGES + 255) / 256, 256, 0, stream>>>(edge_index, edge_dirs, cur,
                                                         esort, hmax, N_EDGES);
    k_cvt_prep<<<(N_NODES * IN_DIM + 255) / 256, 256, 0, stream>>>(
        node_features, X_bf, N_NODES * IN_DIM, b_f, b_b, b_ih, b_hh, bfb, brz);
    k_transpose_all<<<8704, 256, 0, stream>>>(W_in, W_f, W_b, W_ih, W_hh,
                                              Wint, Wft, Wbt, Wiht, Whht);

    dim3 gg(M_PAD / BM, HID / BN);        // 80 x 4
    dim3 gg3(M_PAD / GM, 3 * HID / GN);   // 40 x 12

    // ---- input projection: h = X @ W_in + b_in (fp16) ----
    gemm_f16<<<gg, NTHR, 0, stream>>>(X_bf, Wint, nullptr, nullptr,
                                      nullptr, b_in, nullptr, nullptr, nullptr,
                                      h_bf, N_NODES, IN_DIM, 0);

    const size_t HH = (size_t)HID * HID;
    for (int layer = 0; layer < 8; ++layer) {
        k_agg<<<N_NODES, 128, 0, stream>>>(h_bf, offs, esort, bufA, bufB, bufC);
        // msg = aggF@W_f + aggB@W_b + aggU + (b_f+b_b)
        gemm_f16<<<gg, NTHR, 0, stream>>>(bufA, Wft, bufB, Wbt, bufC, bfb,
                                          nullptr, nullptr, nullptr,
                                          msg, N_NODES, HID, 0);
        // r,z,hn fused over N=3072 -> bufA, bufB, bufC
        gemm_gates<<<gg3, 1024, 0, stream>>>(msg, h_bf, Wiht, Whht, brz, b_hh,
                                             bufA, bufB, bufC, N_NODES);
        // h = relu((1-z)*tanh(msg@Wih_n + b_ih_n + r*hn) + z*h)  (in place)
        gemm_f16<<<gg, NTHR, 0, stream>>>(msg, Wiht + 2 * HH, nullptr, nullptr,
                                          nullptr, b_ih + 2 * HID,
                                          bufA, bufB, bufC,
                                          h_bf, N_NODES, HID, 2);
    }

    // ---- readout ----
    {
        dim3 gm(1, 50);
        k_colmax<<<gm, 128, 0, stream>>>(h_bf, hmax);
    }
    k_readout<<<1, 1024, 0, stream>>>(hmax, W_r1, b_r1, W_r2, b_r2, out);
}

// Round 13
// 3057.055 us; speedup vs baseline: 1.0668x; 1.0668x over previous
//
#include <hip/hip_runtime.h>
#include <hip/hip_bf16.h>
#include <math.h>

#define N_NODES 10000
#define N_EDGES 160000
#define IN_DIM  512
#define HID     1024
#define M_PAD   10240   // 80 * 128

typedef _Float16 half8 __attribute__((ext_vector_type(8)));
typedef float    floatx4 __attribute__((ext_vector_type(4)));

__device__ inline void gld16(const void* g, void* l) {
    __builtin_amdgcn_global_load_lds(
        (const __attribute__((address_space(1))) unsigned int*)g,
        (__attribute__((address_space(3))) unsigned int*)l, 16, 0, 0);
}

__device__ inline float sig_(float x)  { return 1.0f / (1.0f + __expf(-x)); }
__device__ inline float tanh_(float x) { return 2.0f / (1.0f + __expf(-2.0f * x)) - 1.0f; }

// Supertile swizzle: 4 consecutive linear block ids share one x (A-tile).
// gemm_f16 only (r6 win); gates without (r6 loss).
__device__ inline void swizzle_xy(int& bx, int& by) {
    int lin = blockIdx.y * gridDim.x + blockIdx.x;
    int per = gridDim.x << 2;
    int sup = lin / per;
    int rem = lin - sup * per;
    by = (sup << 2) + (rem & 3);
    bx = rem >> 2;
}

// ---------------------------------------------------------------------------
// CSR build
// ---------------------------------------------------------------------------
__global__ void k_hist(const int* __restrict__ ei, int* __restrict__ deg, int ne) {
    int e = blockIdx.x * blockDim.x + threadIdx.x;
    if (e < ne) atomicAdd(&deg[ei[2 * e + 1]], 1);
}

// exclusive scan; writes offs[0..n] and a second copy into cur[0..n-1]
__global__ void k_scan(const int* __restrict__ deg, int* __restrict__ offs,
                       int* __restrict__ cur, int n) {
    __shared__ int s[1024];
    __shared__ int base_s;
    int t = threadIdx.x;
    if (t == 0) base_s = 0;
    __syncthreads();
    int nchunk = (n + 1023) / 1024;
    for (int ch = 0; ch < nchunk; ++ch) {
        int i = ch * 1024 + t;
        int v = (i < n) ? deg[i] : 0;
        s[t] = v;
        __syncthreads();
        for (int off = 1; off < 1024; off <<= 1) {
            int add = (t >= off) ? s[t - off] : 0;
            __syncthreads();
            s[t] += add;
            __syncthreads();
        }
        int incl = s[t];
        int base = base_s;
        if (i < n) { int ex = base + incl - v; offs[i] = ex; cur[i] = ex; }
        __syncthreads();
        if (t == 1023) base_s = base + s[1023];
        __syncthreads();
    }
    if (t == 0) offs[n] = base_s;
}

// scatter packed (dir<<16)|src; also zero-inits hmax (cols < HID)
__global__ void k_scatter(const int* __restrict__ ei, const int* __restrict__ ed,
                          int* __restrict__ cur, int* __restrict__ esort,
                          float* __restrict__ hmax, int ne) {
    int e = blockIdx.x * blockDim.x + threadIdx.x;
    if (e < HID) hmax[e] = 0.f;
    if (e < ne) {
        int dst = ei[2 * e + 1];
        int pos = atomicAdd(&cur[dst], 1);
        esort[pos] = (ed[e] << 16) | ei[2 * e];
    }
}

// fp32->fp16 feature convert + bias precompute (fused)
__global__ void k_cvt_prep(const float* __restrict__ X, _Float16* __restrict__ Xh,
                           int n, const float* __restrict__ b_f,
                           const float* __restrict__ b_b,
                           const float* __restrict__ b_ih,
                           const float* __restrict__ b_hh,
                           float* __restrict__ bfb, float* __restrict__ brz) {
    int i = blockIdx.x * blockDim.x + threadIdx.x;
    if (i < n) Xh[i] = (_Float16)X[i];
    if (i < HID) bfb[i] = b_f[i] + b_b[i];
    if (i < 2 * HID) brz[i] = b_ih[i] + b_hh[i];
}

// All 5 weight transposes (fp32 KxN -> fp16 NxK) in one dispatch via tile table
__global__ __launch_bounds__(256) void k_transpose_all(
    const float* __restrict__ W_in, const float* __restrict__ W_f,
    const float* __restrict__ W_b, const float* __restrict__ W_ih,
    const float* __restrict__ W_hh,
    _Float16* __restrict__ Wint, _Float16* __restrict__ Wft,
    _Float16* __restrict__ Wbt, _Float16* __restrict__ Wiht,
    _Float16* __restrict__ Whht) {
    int tid = blockIdx.x;
    const float* in; _Float16* outp; int K, N, loc;
    if (tid < 512)       { in = W_in; outp = Wint; K = IN_DIM; N = HID;     loc = tid; }
    else if (tid < 1536) { in = W_f;  outp = Wft;  K = HID;    N = HID;     loc = tid - 512; }
    else if (tid < 2560) { in = W_b;  outp = Wbt;  K = HID;    N = HID;     loc = tid - 1536; }
    else if (tid < 5632) { in = W_ih; outp = Wiht; K = HID;    N = 3 * HID; loc = tid - 2560; }
    else                 { in = W_hh; outp = Whht; K = HID;    N = 3 * HID; loc = tid - 5632; }
    int nt = N >> 5;
    int n0 = (loc % nt) * 32, k0 = (loc / nt) * 32;
    __shared__ float tile[32][33];
    int tx = threadIdx.x & 31, ty = threadIdx.x >> 5;   // 32 x 8
#pragma unroll
    for (int r = 0; r < 4; ++r) {
        int k = k0 + ty + r * 8;
        tile[ty + r * 8][tx] = in[(size_t)k * N + n0 + tx];
    }
    __syncthreads();
#pragma unroll
    for (int r = 0; r < 4; ++r) {
        int n = n0 + ty + r * 8;
        outp[(size_t)n * K + k0 + tx] = (_Float16)tile[tx][ty + r * 8];
    }
}

// ---------------------------------------------------------------------------
// Aggregation: one block (128 thr) per node, 8 fp16 channels each.
// 4x edge unroll; wave-uniform branches with DIRECT register arrays
// (r10 lesson: runtime-selected pointer -> scratch spill, 517 MB writes).
// Structural floor ~90 us/layer: random 2KB row-gather at ~3.6 TB/s (r11).
// ---------------------------------------------------------------------------
__global__ __launch_bounds__(128) void k_agg(
    const _Float16* __restrict__ h, const int* __restrict__ offs,
    const int* __restrict__ esort,
    _Float16* __restrict__ aggF, _Float16* __restrict__ aggB,
    _Float16* __restrict__ aggU) {
    int node = blockIdx.x;
    int c = threadIdx.x * 8;
    float f[8], b[8], u[8];
#pragma unroll
    for (int j = 0; j < 8; ++j) { f[j] = 0.f; b[j] = 0.f; u[j] = 0.f; }
    int beg = offs[node], end = offs[node + 1];
    int e = beg;
    for (; e + 4 <= end; e += 4) {
        int pk0 = esort[e + 0];
        int pk1 = esort[e + 1];
        int pk2 = esort[e + 2];
        int pk3 = esort[e + 3];
        half8 v0 = *(const half8*)(h + ((size_t)(pk0 & 0xFFFF) << 10) + c);
        half8 v1 = *(const half8*)(h + ((size_t)(pk1 & 0xFFFF) << 10) + c);
        half8 v2 = *(const half8*)(h + ((size_t)(pk2 & 0xFFFF) << 10) + c);
        half8 v3 = *(const half8*)(h + ((size_t)(pk3 & 0xFFFF) << 10) + c);
        int d0 = pk0 >> 16, d1 = pk1 >> 16, d2 = pk2 >> 16, d3 = pk3 >> 16;
        if (d0 == 0) {
#pragma unroll
            for (int j = 0; j < 8; ++j) f[j] += (float)v0[j];
        } else if (d0 == 1) {
#pragma unroll
            for (int j = 0; j < 8; ++j) b[j] += (float)v0[j];
        } else {
#pragma unroll
            for (int j = 0; j < 8; ++j) u[j] += (float)v0[j];
        }
        if (d1 == 0) {
#pragma unroll
            for (int j = 0; j < 8; ++j) f[j] += (float)v1[j];
        } else if (d1 == 1) {
#pragma unroll
            for (int j = 0; j < 8; ++j) b[j] += (float)v1[j];
        } else {
#pragma unroll
            for (int j = 0; j < 8; ++j) u[j] += (float)v1[j];
        }
        if (d2 == 0) {
#pragma unroll
            for (int j = 0; j < 8; ++j) f[j] += (float)v2[j];
        } else if (d2 == 1) {
#pragma unroll
            for (int j = 0; j < 8; ++j) b[j] += (float)v2[j];
        } else {
#pragma unroll
            for (int j = 0; j < 8; ++j) u[j] += (float)v2[j];
        }
        if (d3 == 0) {
#pragma unroll
            for (int j = 0; j < 8; ++j) f[j] += (float)v3[j];
        } else if (d3 == 1) {
#pragma unroll
            for (int j = 0; j < 8; ++j) b[j] += (float)v3[j];
        } else {
#pragma unroll
            for (int j = 0; j < 8; ++j) u[j] += (float)v3[j];
        }
    }
    for (; e < end; ++e) {
        int pk = esort[e];
        half8 v = *(const half8*)(h + ((size_t)(pk & 0xFFFF) << 10) + c);
        int d = pk >> 16;
        if (d == 0) {
#pragma unroll
            for (int j = 0; j < 8; ++j) f[j] += (float)v[j];
        } else if (d == 1) {
#pragma unroll
            for (int j = 0; j < 8; ++j) b[j] += (float)v[j];
        } else {
#pragma unroll
            for (int j = 0; j < 8; ++j) u[j] += (float)v[j];
        }
    }
    size_t o = (size_t)node * HID + c;
    half8 vf, vb, vu;
#pragma unroll
    for (int j = 0; j < 8; ++j) {
        vf[j] = (_Float16)f[j]; vb[j] = (_Float16)b[j]; vu[j] = (_Float16)u[j];
    }
    *(half8*)(aggF + o) = vf;
    *(half8*)(aggB + o) = vb;
    *(half8*)(aggU + o) = vu;
}

// ---------------------------------------------------------------------------
// fp16 MFMA GEMM, 128x256 tile, BK=32, 512 thr = 8 waves (2m x 4n), each wave
// a 64x64 microtile of 4x4 mfma_f32_16x16x32_f16. Output width fixed = HID.
// NOTE: VGPR budget sits at the 4-waves/SIMD boundary (60 VGPR + 64 acc);
// any VGPR creep halves occupancy (r7: BK=64 -> 80 VGPR -> 1 blk/CU).
// 2 blocks/CU is essential: inter-block overlap hides the barrier drain
// (r12: single 1024-thr block/CU -> no overlap -> 154->180 us regression).
// epi 0: v = acc+bias [+U]; Cbf = v
// epi 2: GRU in place: hv=Cbf; nn=tanh(acc+bias+R*HG); Cbf=relu((1-Z)nn+Z*hv)
// ---------------------------------------------------------------------------
#define BM 128
#define BN 256
#define BK 32
#define NTHR 512

__global__ __launch_bounds__(NTHR) void gemm_f16(
    const _Float16* __restrict__ A1, const _Float16* __restrict__ B1t,
    const _Float16* __restrict__ A2, const _Float16* __restrict__ B2t,
    const _Float16* __restrict__ U, const float* __restrict__ bias,
    const _Float16* __restrict__ R, const _Float16* __restrict__ Zg,
    const _Float16* __restrict__ HG, _Float16* __restrict__ Cbf,
    int M, int K, int epi) {
    __shared__ _Float16 As[BM * BK];   // 8 KB
    __shared__ _Float16 Bs[BN * BK];   // 16 KB
    int t = threadIdx.x;
    int bx, by;
    swizzle_xy(bx, by);
    int m0 = bx * BM, n0 = by * BN;
    int wid = t >> 6, lane = t & 63;
    int wm = wid & 1, wn = wid >> 1;            // 2 x 4 wave grid
    int quad = lane >> 4, mr = lane & 15;

    floatx4 acc[4][4] = {};

    int npair = (A2 != nullptr) ? 2 : 1;
    for (int p = 0; p < npair; ++p) {
        const _Float16* A = p ? A2 : A1;
        const _Float16* B = p ? B2t : B1t;
        for (int k0 = 0; k0 < K; k0 += BK) {
            {   // A tile 128x32: 1 gld16 per thread
                int row = t >> 2;
                int ce = (t & 3) * 8;
                gld16(A + (size_t)(m0 + row) * K + k0 + ce, As + t * 8);
            }
#pragma unroll
            for (int i = 0; i < 2; ++i) {       // B tile 256x32: 2 gld16
                int row = i * 128 + (t >> 2);
                int ce = (t & 3) * 8;
                gld16(B + (size_t)(n0 + row) * K + k0 + ce, Bs + i * 4096 + t * 8);
            }
            __syncthreads();
            half8 af[4], bfr[4];
#pragma unroll
            for (int i = 0; i < 4; ++i)
                af[i] = *(const half8*)(As + (wm * 64 + i * 16 + mr) * 32 + quad * 8);
#pragma unroll
            for (int j = 0; j < 4; ++j)
                bfr[j] = *(const half8*)(Bs + (wn * 64 + j * 16 + mr) * 32 + quad * 8);
#pragma unroll
            for (int i = 0; i < 4; ++i)
#pragma unroll
                for (int j = 0; j < 4; ++j)
                    acc[i][j] = __builtin_amdgcn_mfma_f32_16x16x32_f16(
                        af[i], bfr[j], acc[i][j], 0, 0, 0);
            __syncthreads();
        }
    }

#pragma unroll
    for (int i = 0; i < 4; ++i) {
#pragma unroll
        for (int j = 0; j < 4; ++j) {
            int n = n0 + wn * 64 + j * 16 + mr;
            float bv = bias[n];
#pragma unroll
            for (int r = 0; r < 4; ++r) {
                int m = m0 + wm * 64 + i * 16 + quad * 4 + r;
                if (m >= M) continue;
                size_t idx = (size_t)m * HID + n;
                float v = acc[i][j][r] + bv;
                if (epi == 0) {
                    if (U) v += (float)U[idx];
                    Cbf[idx] = (_Float16)v;
                } else {
                    float rr = (float)R[idx], zz = (float)Zg[idx], hg = (float)HG[idx];
                    float hv = (float)Cbf[idx];
                    float nn = tanh_(v + rr * hg);
                    float o = fmaxf((1.f - zz) * nn + zz * hv, 0.f);
                    Cbf[idx] = (_Float16)o;
                }
            }
        }
    }
}

// ---------------------------------------------------------------------------
// Fused gate GEMM, 128x256 tile, 512 thr (measured-best config; r12's 256x256
// single-block-per-CU variant regressed: no inter-block barrier overlap).
//   ng0 in [0,2048):   C = sigmoid(msg@Wih[n] + h@Whh[n] + brz[n])  (r, z)
//   ng0 in [2048,3072): C = h@Whh[n] + b_hh[n]                      (hn-gate)
// Writes r->bufA, z->bufB, hn->bufC. No block swizzle (r6 regression).
// ---------------------------------------------------------------------------
__global__ __launch_bounds__(NTHR) void gemm_gates(
    const _Float16* __restrict__ msg, const _Float16* __restrict__ hbf,
    const _Float16* __restrict__ Wiht, const _Float16* __restrict__ Whht,
    const float* __restrict__ brz, const float* __restrict__ b_hh,
    _Float16* __restrict__ bufA, _Float16* __restrict__ bufB,
    _Float16* __restrict__ bufC, int M) {
    __shared__ _Float16 As[BM * BK];
    __shared__ _Float16 Bs[BN * BK];
    int t = threadIdx.x;
    int m0 = blockIdx.x * BM;
    int ng0 = blockIdx.y * BN;          // global n in [0, 3072), 256-aligned
    int seg = ng0 >> 10;                // 0=r, 1=z, 2=hn
    int wid = t >> 6, lane = t & 63;
    int wm = wid & 1, wn = wid >> 1;
    int quad = lane >> 4, mr = lane & 15;

    const _Float16* A1 = (seg < 2) ? msg : hbf;
    const _Float16* B1 = ((seg < 2) ? Wiht : Whht) + (size_t)ng0 * HID;
    const _Float16* A2 = hbf;
    const _Float16* B2 = Whht + (size_t)ng0 * HID;
    int npair = (seg < 2) ? 2 : 1;

    floatx4 acc[4][4] = {};
    for (int p = 0; p < npair; ++p) {
        const _Float16* A = p ? A2 : A1;
        const _Float16* B = p ? B2 : B1;
        for (int k0 = 0; k0 < HID; k0 += BK) {
            {
                int row = t >> 2;
                int ce = (t & 3) * 8;
                gld16(A + (size_t)(m0 + row) * HID + k0 + ce, As + t * 8);
            }
#pragma unroll
            for (int i = 0; i < 2; ++i) {
                int row = i * 128 + (t >> 2);
                int ce = (t & 3) * 8;
                gld16(B + (size_t)row * HID + k0 + ce, Bs + i * 4096 + t * 8);
            }
            __syncthreads();
            half8 af[4], bfr[4];
#pragma unroll
            for (int i = 0; i < 4; ++i)
                af[i] = *(const half8*)(As + (wm * 64 + i * 16 + mr) * 32 + quad * 8);
#pragma unroll
            for (int j = 0; j < 4; ++j)
                bfr[j] = *(const half8*)(Bs + (wn * 64 + j * 16 + mr) * 32 + quad * 8);
#pragma unroll
            for (int i = 0; i < 4; ++i)
#pragma unroll
                for (int j = 0; j < 4; ++j)
                    acc[i][j] = __builtin_amdgcn_mfma_f32_16x16x32_f16(
                        af[i], bfr[j], acc[i][j], 0, 0, 0);
            __syncthreads();
        }
    }

    _Float16* Cb = (seg == 0) ? bufA : (seg == 1) ? bufB : bufC;
#pragma unroll
    for (int i = 0; i < 4; ++i) {
#pragma unroll
        for (int j = 0; j < 4; ++j) {
            int n = ng0 + wn * 64 + j * 16 + mr;       // global [0,3072)
            int nloc = n & 1023;
            float bv = (seg < 2) ? brz[n] : b_hh[n];
#pragma unroll
            for (int r = 0; r < 4; ++r) {
                int m = m0 + wm * 64 + i * 16 + quad * 4 + r;
                if (m >= M) continue;
                size_t idx = (size_t)m * HID + nloc;
                float v = acc[i][j][r] + bv;
                Cb[idx] = (_Float16)((seg < 2) ? sig_(v) : v);
            }
        }
    }
}

// ---------------------------------------------------------------------------
// Readout
// ---------------------------------------------------------------------------
// colmax: block = 128 thr x 8 channels (coalesced 2 KB/row); grid (1, 50)
__global__ __launch_bounds__(128) void k_colmax(const _Float16* __restrict__ h,
                                                float* __restrict__ hmax) {
    int c = threadIdx.x * 8;
    int r0 = blockIdx.y * 200;
    int r1 = r0 + 200; if (r1 > N_NODES) r1 = N_NODES;
    float m[8];
#pragma unroll
    for (int j = 0; j < 8; ++j) m[j] = 0.f;             // h >= 0 post-relu
    for (int r = r0; r < r1; ++r) {
        half8 v = *(const half8*)(h + ((size_t)r << 10) + c);
#pragma unroll
        for (int j = 0; j < 8; ++j) m[j] = fmaxf(m[j], (float)v[j]);
    }
#pragma unroll
    for (int j = 0; j < 8; ++j)
        atomicMax((int*)&hmax[c + j], __float_as_int(m[j]));
}

// fused: t1 = relu(hmax@W_r1 + b_r1); out = t1@W_r2 + b_r2  (one block, 1024 thr)
__global__ __launch_bounds__(1024) void k_readout(
    const float* __restrict__ hmax, const float* __restrict__ W1,
    const float* __restrict__ b1, const float* __restrict__ W2,
    const float* __restrict__ b2, float* __restrict__ out) {
    __shared__ float sh[1024];
    int j = threadIdx.x;
    float acc = b1[j];
    for (int k = 0; k < HID; ++k) acc += hmax[k] * W1[(size_t)k * HID + j];
    sh[j] = fmaxf(acc, 0.f) * W2[j];
    __syncthreads();
    for (int st = 512; st > 0; st >>= 1) {
        if (j < st) sh[j] += sh[j + st];
        __syncthreads();
    }
    if (j == 0) out[0] = sh[0] + b2[0];
}

// ---------------------------------------------------------------------------
extern "C" void kernel_launch(void* const* d_in, const int* in_sizes, int n_in,
                              void* d_out, int out_size, void* d_ws, size_t ws_size,
                              hipStream_t stream) {
    const float* node_features = (const float*)d_in[0];
    const int*   edge_index    = (const int*)d_in[1];
    const int*   edge_dirs     = (const int*)d_in[2];
    const float* W_in = (const float*)d_in[3];
    const float* b_in = (const float*)d_in[4];
    const float* W_f  = (const float*)d_in[5];
    const float* b_f  = (const float*)d_in[6];
    const float* W_b  = (const float*)d_in[7];
    const float* b_b  = (const float*)d_in[8];
    const float* W_ih = (const float*)d_in[9];
    const float* b_ih = (const float*)d_in[10];
    const float* W_hh = (const float*)d_in[11];
    const float* b_hh = (const float*)d_in[12];
    const float* W_r1 = (const float*)d_in[13];
    const float* b_r1 = (const float*)d_in[14];
    const float* W_r2 = (const float*)d_in[15];
    const float* b_r2 = (const float*)d_in[16];
    float* out = (float*)d_out;

    // ---- workspace layout ----
    float* ws = (float*)d_ws;
    size_t off = 0;
    auto allocf = [&](size_t n) { float* p = ws + off; off += n; return p; };
    const size_t PH = (size_t)M_PAD * HID;
    float* bfb   = allocf(HID);
    float* brz   = allocf(2 * HID);
    float* hmax  = allocf(HID);
    _Float16* hp = (_Float16*)(ws + off);
    size_t hoff = 0;
    auto alloch = [&](size_t n) { _Float16* p = hp + hoff; hoff += n; return p; };
    _Float16* h_bf  = alloch(PH);       // fp16 GRU state (in-place update)
    _Float16* msg   = alloch(PH);
    _Float16* bufA  = alloch(PH);       // aggF -> r
    _Float16* bufB  = alloch(PH);       // aggB -> z
    _Float16* bufC  = alloch(PH);       // aggU -> hn-gate
    _Float16* X_bf  = alloch((size_t)M_PAD * IN_DIM);
    _Float16* Wint  = alloch((size_t)HID * IN_DIM);
    _Float16* Wft   = alloch((size_t)HID * HID);
    _Float16* Wbt   = alloch((size_t)HID * HID);
    _Float16* Wiht  = alloch((size_t)3 * HID * HID);   // 3072 x 1024 (N x K)
    _Float16* Whht  = alloch((size_t)3 * HID * HID);
    int* ibase = (int*)(hp + hoff);
    int* deg   = ibase;
    int* offs  = ibase + N_NODES;
    int* cur   = offs + N_NODES + 1;
    int* esort = cur + N_NODES;

    // ---- CSR build + prep ----
    hipMemsetAsync(deg, 0, N_NODES * sizeof(int), stream);
    k_hist<<<(N_EDGES + 255) / 256, 256, 0, stream>>>(edge_index, deg, N_EDGES);
    k_scan<<<1, 1024, 0, stream>>>(deg, offs, cur, N_NODES);
    k_scatter<<<(N_EDGES + 255) / 256, 256, 0, stream>>>(edge_index, edge_dirs, cur,
                                                         esort, hmax, N_EDGES);
    k_cvt_prep<<<(N_NODES * IN_DIM + 255) / 256, 256, 0, stream>>>(
        node_features, X_bf, N_NODES * IN_DIM, b_f, b_b, b_ih, b_hh, bfb, brz);
    k_transpose_all<<<8704, 256, 0, stream>>>(W_in, W_f, W_b, W_ih, W_hh,
                                              Wint, Wft, Wbt, Wiht, Whht);

    dim3 gg(M_PAD / BM, HID / BN);        // 80 x 4
    dim3 gg3(M_PAD / BM, 3 * HID / BN);   // 80 x 12

    // ---- input projection: h = X @ W_in + b_in (fp16) ----
    gemm_f16<<<gg, NTHR, 0, stream>>>(X_bf, Wint, nullptr, nullptr,
                                      nullptr, b_in, nullptr, nullptr, nullptr,
                                      h_bf, N_NODES, IN_DIM, 0);

    const size_t HH = (size_t)HID * HID;
    for (int layer = 0; layer < 8; ++layer) {
        k_agg<<<N_NODES, 128, 0, stream>>>(h_bf, offs, esort, bufA, bufB, bufC);
        // msg = aggF@W_f + aggB@W_b + aggU + (b_f+b_b)
        gemm_f16<<<gg, NTHR, 0, stream>>>(bufA, Wft, bufB, Wbt, bufC, bfb,
                                          nullptr, nullptr, nullptr,
                                          msg, N_NODES, HID, 0);
        // r,z,hn fused over N=3072 -> bufA, bufB, bufC
        gemm_gates<<<gg3, NTHR, 0, stream>>>(msg, h_bf, Wiht, Whht, brz, b_hh,
                                             bufA, bufB, bufC, N_NODES);
        // h = relu((1-z)*tanh(msg@Wih_n + b_ih_n + r*hn) + z*h)  (in place)
        gemm_f16<<<gg, NTHR, 0, stream>>>(msg, Wiht + 2 * HH, nullptr, nullptr,
                                          nullptr, b_ih + 2 * HID,
                                          bufA, bufB, bufC,
                                          h_bf, N_NODES, HID, 2);
    }

    // ---- readout ----
    {
        dim3 gm(1, 50);
        k_colmax<<<gm, 128, 0, stream>>>(h_bf, hmax);
    }
    k_readout<<<1, 1024, 0, stream>>>(hmax, W_r1, b_r1, W_r2, b_r2, out);
}